// Round 15
// baseline (212.092 us; speedup 1.0000x reference)
//
#include <hip/hip_runtime.h>
#include <hip/hip_bf16.h>
#include <math.h>

// Problem dims (fixed)
#define C_IN 256
#define HW 128          // H = W = 128
#define NPIX (HW*HW)    // 16384
#define DIM_LOI 128
#define N_LINES 16000
#define N_PTS0 32
#define N_PTS1 8
#define DIM_FC 1024
#define N_LABELS 3

typedef __attribute__((ext_vector_type(8))) short short8;   // 8 bf16 = 4 VGPRs
typedef __attribute__((ext_vector_type(4))) float f32x4;

// ---------------------------------------------------------------------------
// prep_kernel: all input conversions in ONE dispatch (branch on blockIdx).
//  [0,1024)    : transpose+bf16 features (256,16384) -> featsT (16384,256)
//  [1024,2048) : permute_w1  k=c*8+p -> k'=p*128+c, fp32->bf16
//  [2048,3072) : to_bf16 w2
//  [3072,3104) : to_bf16 w_fc1
// ---------------------------------------------------------------------------
__global__ __launch_bounds__(256) void prep_kernel(
    const float* __restrict__ feats, __hip_bfloat16* __restrict__ featsT,
    const float* __restrict__ w1,    __hip_bfloat16* __restrict__ w1p,
    const float* __restrict__ w2,    __hip_bfloat16* __restrict__ w2b,
    const float* __restrict__ wfc1,  __hip_bfloat16* __restrict__ wfc1b)
{
    __shared__ float tile[64][65];
    const int b = blockIdx.x;
    const int t = threadIdx.x;

    if (b < 1024) {
        // ---- transpose features ----
        const int p0 = (b & 255) * 64;
        const int c0 = (b >> 8) * 64;
#pragma unroll
        for (int i = 0; i < 4; ++i) {
            int c = (t >> 4) + i * 16;
            int p4 = (t & 15) * 4;
            float4 v = *(const float4*)(feats + (size_t)(c0 + c) * NPIX + p0 + p4);
            tile[c][p4 + 0] = v.x;
            tile[c][p4 + 1] = v.y;
            tile[c][p4 + 2] = v.z;
            tile[c][p4 + 3] = v.w;
        }
        __syncthreads();
#pragma unroll
        for (int i = 0; i < 2; ++i) {
            int p = (t >> 3) + i * 32;
            int cc = (t & 7) * 8;
            union { __hip_bfloat16 h[8]; uint4 u4; } pk;
#pragma unroll
            for (int j = 0; j < 8; ++j) pk.h[j] = __float2bfloat16(tile[cc + j][p]);
            *(uint4*)(featsT + (size_t)(p0 + p) * C_IN + c0 + cc) = pk.u4;
        }
    } else if (b < 2048) {
        // ---- permute w1 row ----
        float* row = &tile[0][0];
        const int n = b - 1024;
        ((float4*)row)[t] = ((const float4*)(w1 + (size_t)n * 1024))[t];
        __syncthreads();
        unsigned int* dst = (unsigned int*)(w1p + (size_t)n * 1024);
#pragma unroll
        for (int pass = 0; pass < 2; ++pass) {
            int j = pass * 256 + t;
            int k0 = 2 * j, k1 = 2 * j + 1;
            float v0 = row[(k0 & 127) * 8 + (k0 >> 7)];
            float v1 = row[(k1 & 127) * 8 + (k1 >> 7)];
            union { __hip_bfloat16 h[2]; unsigned int u; } pk;
            pk.h[0] = __float2bfloat16(v0);
            pk.h[1] = __float2bfloat16(v1);
            dst[j] = pk.u;
        }
    } else if (b < 3072) {
        int i = (b - 2048) * 256 + t;     // float4 index into w2
        float4 v = *(const float4*)(w2 + (size_t)i * 4);
        union { __hip_bfloat16 h[4]; uint2 u; } pk;
        pk.h[0] = __float2bfloat16(v.x);
        pk.h[1] = __float2bfloat16(v.y);
        pk.h[2] = __float2bfloat16(v.z);
        pk.h[3] = __float2bfloat16(v.w);
        *(uint2*)(w2b + (size_t)i * 4) = pk.u;
    } else {
        int i = (b - 3072) * 256 + t;     // float4 index into w_fc1 (8192 total)
        float4 v = *(const float4*)(wfc1 + (size_t)i * 4);
        union { __hip_bfloat16 h[4]; uint2 u; } pk;
        pk.h[0] = __float2bfloat16(v.x);
        pk.h[1] = __float2bfloat16(v.y);
        pk.h[2] = __float2bfloat16(v.z);
        pk.h[3] = __float2bfloat16(v.w);
        *(uint2*)(wfc1b + (size_t)i * 4) = pk.u;
    }
}

// ---------------------------------------------------------------------------
// Line pool v3. 256 thr = 4 lines x 1 wave; wave = 4 quarter-waves of 16:
// quarter qd handles output points {qd, qd+4}; lane t16 owns channels
// 8*t16..8*t16+7 via uint4 gathers (one 256-B corner row per 16 lanes).
// feat layout k' = p*128 + c (matches permuted w1).
// ---------------------------------------------------------------------------
__global__ __launch_bounds__(256) void pool_kernel(
    const __hip_bfloat16* __restrict__ loi,   // (NPIX, 128) bf16 channel-last
    const float* __restrict__ lines,          // (N_LINES, 4)
    __hip_bfloat16* __restrict__ feat)        // (N_LINES, 1024), k' = p*128+c
{
    __shared__ int   offs[4][N_PTS0][4];      // uint4-index base (pix*16)
    __shared__ float wts[4][N_PTS0][4];
    const int g    = threadIdx.x >> 6;   // line group in block
    const int lane = threadIdx.x & 63;
    const int qd   = lane >> 4;          // quarter: output points qd, qd+4
    const int t16  = lane & 15;          // channel group 8*t16..8*t16+7
    const int l    = blockIdx.x * 4 + g;

    if (lane < N_PTS0) {
        int j = lane;
        float tt = (float)j * (1.0f / 31.0f);
        float U0 = lines[4 * l + 0], U1 = lines[4 * l + 1];
        float V0 = lines[4 * l + 2], V1 = lines[4 * l + 3];
        float px = U0 * tt + V0 * (1.0f - tt) - 0.5f;
        float py = U1 * tt + V1 * (1.0f - tt) - 0.5f;
        float px0 = fminf(fmaxf(floorf(px), 0.0f), 127.0f);
        float py0 = fminf(fmaxf(floorf(py), 0.0f), 127.0f);
        float px1 = fminf(fmaxf(px0 + 1.0f, 0.0f), 127.0f);
        float py1 = fminf(fmaxf(py0 + 1.0f, 0.0f), 127.0f);
        int ix0 = (int)px0, iy0 = (int)py0, ix1 = (int)px1, iy1 = (int)py1;
        float wx0 = px1 - px, wx1 = px - px0;
        float wy0 = py1 - py, wy1 = py - py0;
        offs[g][j][0] = (iy0 * HW + ix0) * 16;
        offs[g][j][1] = (iy1 * HW + ix0) * 16;
        offs[g][j][2] = (iy0 * HW + ix1) * 16;
        offs[g][j][3] = (iy1 * HW + ix1) * 16;
        wts[g][j][0] = wy0 * wx0;
        wts[g][j][1] = wy1 * wx0;
        wts[g][j][2] = wy0 * wx1;
        wts[g][j][3] = wy1 * wx1;
    }
    __syncthreads();

    const uint4* loi4 = (const uint4*)loi;
    uint4* featw = (uint4*)(feat + (size_t)l * (N_PTS1 * DIM_LOI));

#pragma unroll
    for (int p = 0; p < 2; ++p) {
        const int point = qd + 4 * p;   // 0..7
        float b0 = -INFINITY, b1 = -INFINITY, b2 = -INFINITY, b3 = -INFINITY;
        float b4 = -INFINITY, b5 = -INFINITY, b6 = -INFINITY, b7 = -INFINITY;
#pragma unroll
        for (int q = 0; q < 4; ++q) {
            int j = point * 4 + q;
            uint4 v0 = loi4[offs[g][j][0] + t16];
            uint4 v1 = loi4[offs[g][j][1] + t16];
            uint4 v2 = loi4[offs[g][j][2] + t16];
            uint4 v3 = loi4[offs[g][j][3] + t16];
            float w0 = wts[g][j][0], w1 = wts[g][j][1];
            float w2 = wts[g][j][2], w3 = wts[g][j][3];
            float s;
            s = w0 * __uint_as_float(v0.x << 16) + w1 * __uint_as_float(v1.x << 16)
              + w2 * __uint_as_float(v2.x << 16) + w3 * __uint_as_float(v3.x << 16);
            b0 = fmaxf(b0, s);
            s = w0 * __uint_as_float(v0.x & 0xffff0000u) + w1 * __uint_as_float(v1.x & 0xffff0000u)
              + w2 * __uint_as_float(v2.x & 0xffff0000u) + w3 * __uint_as_float(v3.x & 0xffff0000u);
            b1 = fmaxf(b1, s);
            s = w0 * __uint_as_float(v0.y << 16) + w1 * __uint_as_float(v1.y << 16)
              + w2 * __uint_as_float(v2.y << 16) + w3 * __uint_as_float(v3.y << 16);
            b2 = fmaxf(b2, s);
            s = w0 * __uint_as_float(v0.y & 0xffff0000u) + w1 * __uint_as_float(v1.y & 0xffff0000u)
              + w2 * __uint_as_float(v2.y & 0xffff0000u) + w3 * __uint_as_float(v3.y & 0xffff0000u);
            b3 = fmaxf(b3, s);
            s = w0 * __uint_as_float(v0.z << 16) + w1 * __uint_as_float(v1.z << 16)
              + w2 * __uint_as_float(v2.z << 16) + w3 * __uint_as_float(v3.z << 16);
            b4 = fmaxf(b4, s);
            s = w0 * __uint_as_float(v0.z & 0xffff0000u) + w1 * __uint_as_float(v1.z & 0xffff0000u)
              + w2 * __uint_as_float(v2.z & 0xffff0000u) + w3 * __uint_as_float(v3.z & 0xffff0000u);
            b5 = fmaxf(b5, s);
            s = w0 * __uint_as_float(v0.w << 16) + w1 * __uint_as_float(v1.w << 16)
              + w2 * __uint_as_float(v2.w << 16) + w3 * __uint_as_float(v3.w << 16);
            b6 = fmaxf(b6, s);
            s = w0 * __uint_as_float(v0.w & 0xffff0000u) + w1 * __uint_as_float(v1.w & 0xffff0000u)
              + w2 * __uint_as_float(v2.w & 0xffff0000u) + w3 * __uint_as_float(v3.w & 0xffff0000u);
            b7 = fmaxf(b7, s);
        }
        union { __hip_bfloat16 hh[8]; uint4 u; } pk;
        pk.hh[0] = __float2bfloat16(b0);
        pk.hh[1] = __float2bfloat16(b1);
        pk.hh[2] = __float2bfloat16(b2);
        pk.hh[3] = __float2bfloat16(b3);
        pk.hh[4] = __float2bfloat16(b4);
        pk.hh[5] = __float2bfloat16(b5);
        pk.hh[6] = __float2bfloat16(b6);
        pk.hh[7] = __float2bfloat16(b7);
        featw[point * 16 + t16] = pk.u;   // elements point*128 + 8*t16 ..+7
    }
}

// ---------------------------------------------------------------------------
// MFMA bf16 GEMM, BK=64, double-buffered prefetch + XOR chunk swizzle.
// 128x128 tile, 4 waves 2x2, each wave 4x4 of 16x16x32 MFMA.
// LDS layout: row r's logical 16B k-chunk c lives at slot c ^ (r & 3).
// Fragment read offset (quad ^ row)&3 spreads each 8-lane issue group over
// 4 bank-quartets at 2-way aliasing (free, m136) instead of 4-way.
// Staging stays coalesced: the 4 lanes of a row-group read the same 64-B
// global segment, chunks permuted; LDS dest (base + lane*16B) untouched.
// XCD-aware swizzle: lid%8 = XCD, n fastest -> A-tile reused within one XCD.
// ---------------------------------------------------------------------------
__global__ __launch_bounds__(256) void mfma_gemm(
    const __hip_bfloat16* __restrict__ A,   // (M, K) row-major
    const __hip_bfloat16* __restrict__ B,   // (N, K) row-major (= B^T)
    const float* __restrict__ bias,         // (N)
    __hip_bfloat16* __restrict__ out,       // (M, N)
    int M, int N, int K, int n_tiles)
{
    __shared__ __hip_bfloat16 As[2][128 * 64];   // 32 KB
    __shared__ __hip_bfloat16 Bs[2][128 * 64];   // 32 KB
    const int tid  = threadIdx.x;
    const int lane = tid & 63;
    const int wave = tid >> 6;
    const int wr = wave >> 1, wc = wave & 1;    // 2x2 wave grid
    const int quad = lane >> 4;
    const int l16  = lane & 15;

    // XCD-aware relabel (grid must be divisible by 8)
    const int lid = blockIdx.x;
    const int per = gridDim.x >> 3;
    const int g   = (lid & 7) * per + (lid >> 3);
    const int n0 = (g % n_tiles) * 128;
    const int m0 = (g / n_tiles) * 128;

    f32x4 acc[4][4];
#pragma unroll
    for (int i = 0; i < 4; ++i)
#pragma unroll
        for (int j = 0; j < 4; ++j) { f32x4 z = {0.f, 0.f, 0.f, 0.f}; acc[i][j] = z; }

    // ---- stage helper (4 sites x 256 thr x 16 B per matrix) ----
    // phys chunk li: panel=li>>9, row=(li&511)>>2, slot=li&3;
    // slot holds source chunk c = slot ^ (row&3)  (XOR is self-inverse).
    auto stage = [&](int k0, int buf) {
#pragma unroll
        for (int s = 0; s < 4; ++s) {
            int li   = s * 256 + tid;          // chunk 0..1023
            int row  = (li & 511) >> 2;        // 0..127
            int c    = (li ^ row) & 3;         // XOR-swizzled source chunk
            int ke   = (li >> 9) * 32 + c * 8; // k element offset 0..63
            const __hip_bfloat16* ga = A + (size_t)(m0 + row) * K + k0 + ke;
            const __hip_bfloat16* gb = B + (size_t)(n0 + row) * K + k0 + ke;
            int chunk = s * 256 + (tid & ~63); // wave-uniform base chunk
            __builtin_amdgcn_global_load_lds(
                (const __attribute__((address_space(1))) unsigned int*)ga,
                (__attribute__((address_space(3))) unsigned int*)(As[buf] + chunk * 8),
                16, 0, 0);
            __builtin_amdgcn_global_load_lds(
                (const __attribute__((address_space(1))) unsigned int*)gb,
                (__attribute__((address_space(3))) unsigned int*)(Bs[buf] + chunk * 8),
                16, 0, 0);
        }
    };

    const int nk = K >> 6;
    stage(0, 0);
    __syncthreads();                 // buffer 0 ready

    for (int kt = 0; kt < nk; ++kt) {
        const int cur = kt & 1;
        if (kt + 1 < nk) stage((kt + 1) << 6, cur ^ 1);   // async prefetch

        // ---- compute from buffer cur: two 32-k halves (XOR-swizzled read) ----
#pragma unroll
        for (int kh = 0; kh < 2; ++kh) {
            const short* ap = (const short*)As[cur] + kh * 4096;
            const short* bp = (const short*)Bs[cur] + kh * 4096;
            short8 af[4], bf[4];
#pragma unroll
            for (int mt = 0; mt < 4; ++mt) {
                int row = wr * 64 + mt * 16 + l16;
                af[mt] = *(const short8*)(ap + row * 32 + (((quad ^ row) & 3) << 3));
            }
#pragma unroll
            for (int nt = 0; nt < 4; ++nt) {
                int row = wc * 64 + nt * 16 + l16;
                bf[nt] = *(const short8*)(bp + row * 32 + (((quad ^ row) & 3) << 3));
            }
#pragma unroll
            for (int mt = 0; mt < 4; ++mt)
#pragma unroll
                for (int nt = 0; nt < 4; ++nt)
                    acc[mt][nt] = __builtin_amdgcn_mfma_f32_16x16x32_bf16(
                        af[mt], bf[nt], acc[mt][nt], 0, 0, 0);
        }
        __syncthreads();   // drains prefetch (overlapped) + releases cur buffer
    }

    // ---- epilogue: C row = quad*4 + r, col = l16 ----
#pragma unroll
    for (int nt = 0; nt < 4; ++nt) {
        int n = n0 + wc * 64 + nt * 16 + l16;
        float bv = bias[n];
#pragma unroll
        for (int mt = 0; mt < 4; ++mt) {
            int mbase = m0 + wr * 64 + mt * 16 + quad * 4;
#pragma unroll
            for (int r = 0; r < 4; ++r) {
                float v = acc[mt][nt][r] + bv;
                v = v > 0.0f ? v : 0.0f;
                out[(size_t)(mbase + r) * N + n] = (__hip_bfloat16)v;
            }
        }
    }
}

// ---------------------------------------------------------------------------
// Head: one wave per line, uint4 x-loads (16 B/lane, 2 iters):
// logits[l][n] = sum_k x2[l][k]*w3[n][k] + b3[n]
// ---------------------------------------------------------------------------
__global__ __launch_bounds__(256) void head_kernel(
    const __hip_bfloat16* __restrict__ x2,  // (N_LINES, 1024) bf16
    const float* __restrict__ w3,           // (3, 1024)
    const float* __restrict__ b3,           // (3)
    float* __restrict__ out)                // (N_LINES, 3)
{
    const int gtid = blockIdx.x * blockDim.x + threadIdx.x;
    const int l = gtid >> 6;
    const int lane = threadIdx.x & 63;
    if (l >= N_LINES) return;
    const __hip_bfloat16* xr = x2 + (size_t)l * DIM_FC;
    float s0 = 0.0f, s1 = 0.0f, s2 = 0.0f;
#pragma unroll
    for (int it = 0; it < 2; ++it) {
        int k = it * 512 + lane * 8;
        uint4 xv = *(const uint4*)(xr + k);
        float x[8];
        x[0] = __uint_as_float(xv.x << 16);
        x[1] = __uint_as_float(xv.x & 0xffff0000u);
        x[2] = __uint_as_float(xv.y << 16);
        x[3] = __uint_as_float(xv.y & 0xffff0000u);
        x[4] = __uint_as_float(xv.z << 16);
        x[5] = __uint_as_float(xv.z & 0xffff0000u);
        x[6] = __uint_as_float(xv.w << 16);
        x[7] = __uint_as_float(xv.w & 0xffff0000u);
#pragma unroll
        for (int h = 0; h < 2; ++h) {
            int kk = k + h * 4;
            float4 wa = *(const float4*)(w3 + 0 * DIM_FC + kk);
            float4 wb = *(const float4*)(w3 + 1 * DIM_FC + kk);
            float4 wc = *(const float4*)(w3 + 2 * DIM_FC + kk);
            s0 += x[h*4+0] * wa.x + x[h*4+1] * wa.y + x[h*4+2] * wa.z + x[h*4+3] * wa.w;
            s1 += x[h*4+0] * wb.x + x[h*4+1] * wb.y + x[h*4+2] * wb.z + x[h*4+3] * wb.w;
            s2 += x[h*4+0] * wc.x + x[h*4+1] * wc.y + x[h*4+2] * wc.z + x[h*4+3] * wc.w;
        }
    }
#pragma unroll
    for (int off = 32; off > 0; off >>= 1) {
        s0 += __shfl_xor(s0, off);
        s1 += __shfl_xor(s1, off);
        s2 += __shfl_xor(s2, off);
    }
    if (lane == 0) {
        out[(size_t)l * 3 + 0] = s0 + b3[0];
        out[(size_t)l * 3 + 1] = s1 + b3[1];
        out[(size_t)l * 3 + 2] = s2 + b3[2];
    }
}

// ---------------------------------------------------------------------------
extern "C" void kernel_launch(void* const* d_in, const int* in_sizes, int n_in,
                              void* d_out, int out_size, void* d_ws, size_t ws_size,
                              hipStream_t stream) {
    const float* features = (const float*)d_in[0];  // (1,256,128,128)
    const float* lines    = (const float*)d_in[1];  // (16000,4)
    const float* w_fc1    = (const float*)d_in[2];  // (128,256)
    const float* b_fc1    = (const float*)d_in[3];  // (128)
    const float* w1       = (const float*)d_in[4];  // (1024,1024)
    const float* b1       = (const float*)d_in[5];  // (1024)
    const float* w2       = (const float*)d_in[6];  // (1024,1024)
    const float* b2       = (const float*)d_in[7];  // (1024)
    const float* w3       = (const float*)d_in[8];  // (3,1024)
    const float* b3       = (const float*)d_in[9];  // (3)
    float* out = (float*)d_out;

    char* ws = (char*)d_ws;
    __hip_bfloat16* loi    = (__hip_bfloat16*)ws;
    __hip_bfloat16* featb  = (__hip_bfloat16*)(ws + (size_t)8 * 1024 * 1024);
    __hip_bfloat16* x1b    = (__hip_bfloat16*)(ws + (size_t)40 * 1024 * 1024);
    __hip_bfloat16* x2b    = featb;   // reuse (featb dead after GEMM1)
    __hip_bfloat16* w1b    = (__hip_bfloat16*)(ws + (size_t)72 * 1024 * 1024);
    __hip_bfloat16* w2b    = (__hip_bfloat16*)(ws + (size_t)74 * 1024 * 1024);
    __hip_bfloat16* featsT = (__hip_bfloat16*)(ws + (size_t)76 * 1024 * 1024);
    __hip_bfloat16* wfc1b  = (__hip_bfloat16*)(ws + (size_t)84 * 1024 * 1024);

    // 0) all prep in one dispatch
    prep_kernel<<<dim3(3104), 256, 0, stream>>>(
        features, featsT, w1, w1b, w2, w2b, w_fc1, wfc1b);

    // 1) conv1x1 as MFMA GEMM (grid 128, 1 n-tile, K=256 -> 4 iters)
    mfma_gemm<<<dim3(NPIX / 128), 256, 0, stream>>>(
        featsT, wfc1b, b_fc1, loi, NPIX, DIM_LOI, C_IN, 1);

    // 2) line pooling -> featb (16000,1024) bf16, k' = p*128+c
    pool_kernel<<<dim3(N_LINES / 4), 256, 0, stream>>>(loi, lines, featb);

    // 3) x1 = relu(feat @ w1p^T + b1)   grid 1000 = 125 m x 8 n
    mfma_gemm<<<dim3((N_LINES / 128) * (DIM_FC / 128)), 256, 0, stream>>>(
        featb, w1b, b1, x1b, N_LINES, DIM_FC, DIM_FC, DIM_FC / 128);

    // 4) x2 = relu(x1 @ w2^T + b2)
    mfma_gemm<<<dim3((N_LINES / 128) * (DIM_FC / 128)), 256, 0, stream>>>(
        x1b, w2b, b2, x2b, N_LINES, DIM_FC, DIM_FC, DIM_FC / 128);

    // 5) logits = x2 @ w3^T + b3
    head_kernel<<<dim3((N_LINES * 64 + 255) / 256), 256, 0, stream>>>(x2b, w3, b3, out);
}

// Round 16
// 209.704 us; speedup vs baseline: 1.0114x; 1.0114x over previous
//
#include <hip/hip_runtime.h>
#include <hip/hip_bf16.h>
#include <math.h>

// Problem dims (fixed)
#define C_IN 256
#define HW 128          // H = W = 128
#define NPIX (HW*HW)    // 16384
#define DIM_LOI 128
#define N_LINES 16000
#define N_PTS0 32
#define N_PTS1 8
#define DIM_FC 1024
#define N_LABELS 3

typedef __attribute__((ext_vector_type(8))) short short8;   // 8 bf16 = 4 VGPRs
typedef __attribute__((ext_vector_type(4))) float f32x4;

// ---------------------------------------------------------------------------
// prep_kernel: all input conversions in ONE dispatch (branch on blockIdx).
//  [0,1024)    : transpose+bf16 features (256,16384) -> featsT (16384,256)
//  [1024,2048) : permute_w1  k=c*8+p -> k'=p*128+c, fp32->bf16
//  [2048,3072) : to_bf16 w2
//  [3072,3104) : to_bf16 w_fc1
// ---------------------------------------------------------------------------
__global__ __launch_bounds__(256) void prep_kernel(
    const float* __restrict__ feats, __hip_bfloat16* __restrict__ featsT,
    const float* __restrict__ w1,    __hip_bfloat16* __restrict__ w1p,
    const float* __restrict__ w2,    __hip_bfloat16* __restrict__ w2b,
    const float* __restrict__ wfc1,  __hip_bfloat16* __restrict__ wfc1b)
{
    __shared__ float tile[64][65];
    const int b = blockIdx.x;
    const int t = threadIdx.x;

    if (b < 1024) {
        // ---- transpose features ----
        const int p0 = (b & 255) * 64;
        const int c0 = (b >> 8) * 64;
#pragma unroll
        for (int i = 0; i < 4; ++i) {
            int c = (t >> 4) + i * 16;
            int p4 = (t & 15) * 4;
            float4 v = *(const float4*)(feats + (size_t)(c0 + c) * NPIX + p0 + p4);
            tile[c][p4 + 0] = v.x;
            tile[c][p4 + 1] = v.y;
            tile[c][p4 + 2] = v.z;
            tile[c][p4 + 3] = v.w;
        }
        __syncthreads();
#pragma unroll
        for (int i = 0; i < 2; ++i) {
            int p = (t >> 3) + i * 32;
            int cc = (t & 7) * 8;
            union { __hip_bfloat16 h[8]; uint4 u4; } pk;
#pragma unroll
            for (int j = 0; j < 8; ++j) pk.h[j] = __float2bfloat16(tile[cc + j][p]);
            *(uint4*)(featsT + (size_t)(p0 + p) * C_IN + c0 + cc) = pk.u4;
        }
    } else if (b < 2048) {
        // ---- permute w1 row ----
        float* row = &tile[0][0];
        const int n = b - 1024;
        ((float4*)row)[t] = ((const float4*)(w1 + (size_t)n * 1024))[t];
        __syncthreads();
        unsigned int* dst = (unsigned int*)(w1p + (size_t)n * 1024);
#pragma unroll
        for (int pass = 0; pass < 2; ++pass) {
            int j = pass * 256 + t;
            int k0 = 2 * j, k1 = 2 * j + 1;
            float v0 = row[(k0 & 127) * 8 + (k0 >> 7)];
            float v1 = row[(k1 & 127) * 8 + (k1 >> 7)];
            union { __hip_bfloat16 h[2]; unsigned int u; } pk;
            pk.h[0] = __float2bfloat16(v0);
            pk.h[1] = __float2bfloat16(v1);
            dst[j] = pk.u;
        }
    } else if (b < 3072) {
        int i = (b - 2048) * 256 + t;     // float4 index into w2
        float4 v = *(const float4*)(w2 + (size_t)i * 4);
        union { __hip_bfloat16 h[4]; uint2 u; } pk;
        pk.h[0] = __float2bfloat16(v.x);
        pk.h[1] = __float2bfloat16(v.y);
        pk.h[2] = __float2bfloat16(v.z);
        pk.h[3] = __float2bfloat16(v.w);
        *(uint2*)(w2b + (size_t)i * 4) = pk.u;
    } else {
        int i = (b - 3072) * 256 + t;     // float4 index into w_fc1 (8192 total)
        float4 v = *(const float4*)(wfc1 + (size_t)i * 4);
        union { __hip_bfloat16 h[4]; uint2 u; } pk;
        pk.h[0] = __float2bfloat16(v.x);
        pk.h[1] = __float2bfloat16(v.y);
        pk.h[2] = __float2bfloat16(v.z);
        pk.h[3] = __float2bfloat16(v.w);
        *(uint2*)(wfc1b + (size_t)i * 4) = pk.u;
    }
}

// ---------------------------------------------------------------------------
// Line pool v4. 256 thr = 2 lines x 2 waves; a line's 128 threads form 8
// quarter-waves of 16; quarter q handles output point q; lane t16 owns
// channels 8*t16..8*t16+7 via uint4 gathers. 16 loads/lane (v3 had 32) ->
// half the serial vmem chain, 2x wave parallelism (8000 blocks).
// feat layout k' = p*128 + c (matches permuted w1).
// ---------------------------------------------------------------------------
__global__ __launch_bounds__(256) void pool_kernel(
    const __hip_bfloat16* __restrict__ loi,   // (NPIX, 128) bf16 channel-last
    const float* __restrict__ lines,          // (N_LINES, 4)
    __hip_bfloat16* __restrict__ feat)        // (N_LINES, 1024), k' = p*128+c
{
    __shared__ int   offs[2][N_PTS0][4];      // uint4-index base (pix*16)
    __shared__ float wts[2][N_PTS0][4];
    const int h     = threadIdx.x >> 7;  // line half of block (0,1)
    const int lt    = threadIdx.x & 127; // thread within line
    const int point = lt >> 4;           // 0..7 output point
    const int t16   = lt & 15;           // channel group 8*t16..8*t16+7
    const int l     = blockIdx.x * 2 + h;

    if (lt < N_PTS0) {
        int j = lt;
        float tt = (float)j * (1.0f / 31.0f);
        float U0 = lines[4 * l + 0], U1 = lines[4 * l + 1];
        float V0 = lines[4 * l + 2], V1 = lines[4 * l + 3];
        float px = U0 * tt + V0 * (1.0f - tt) - 0.5f;
        float py = U1 * tt + V1 * (1.0f - tt) - 0.5f;
        float px0 = fminf(fmaxf(floorf(px), 0.0f), 127.0f);
        float py0 = fminf(fmaxf(floorf(py), 0.0f), 127.0f);
        float px1 = fminf(fmaxf(px0 + 1.0f, 0.0f), 127.0f);
        float py1 = fminf(fmaxf(py0 + 1.0f, 0.0f), 127.0f);
        int ix0 = (int)px0, iy0 = (int)py0, ix1 = (int)px1, iy1 = (int)py1;
        float wx0 = px1 - px, wx1 = px - px0;
        float wy0 = py1 - py, wy1 = py - py0;
        offs[h][j][0] = (iy0 * HW + ix0) * 16;
        offs[h][j][1] = (iy1 * HW + ix0) * 16;
        offs[h][j][2] = (iy0 * HW + ix1) * 16;
        offs[h][j][3] = (iy1 * HW + ix1) * 16;
        wts[h][j][0] = wy0 * wx0;
        wts[h][j][1] = wy1 * wx0;
        wts[h][j][2] = wy0 * wx1;
        wts[h][j][3] = wy1 * wx1;
    }
    __syncthreads();

    const uint4* loi4 = (const uint4*)loi;
    uint4* featw = (uint4*)(feat + (size_t)l * (N_PTS1 * DIM_LOI));

    float b0 = -INFINITY, b1 = -INFINITY, b2 = -INFINITY, b3 = -INFINITY;
    float b4 = -INFINITY, b5 = -INFINITY, b6 = -INFINITY, b7 = -INFINITY;
#pragma unroll
    for (int q = 0; q < 4; ++q) {
        int j = point * 4 + q;
        uint4 v0 = loi4[offs[h][j][0] + t16];
        uint4 v1 = loi4[offs[h][j][1] + t16];
        uint4 v2 = loi4[offs[h][j][2] + t16];
        uint4 v3 = loi4[offs[h][j][3] + t16];
        float w0 = wts[h][j][0], w1 = wts[h][j][1];
        float w2 = wts[h][j][2], w3 = wts[h][j][3];
        float s;
        s = w0 * __uint_as_float(v0.x << 16) + w1 * __uint_as_float(v1.x << 16)
          + w2 * __uint_as_float(v2.x << 16) + w3 * __uint_as_float(v3.x << 16);
        b0 = fmaxf(b0, s);
        s = w0 * __uint_as_float(v0.x & 0xffff0000u) + w1 * __uint_as_float(v1.x & 0xffff0000u)
          + w2 * __uint_as_float(v2.x & 0xffff0000u) + w3 * __uint_as_float(v3.x & 0xffff0000u);
        b1 = fmaxf(b1, s);
        s = w0 * __uint_as_float(v0.y << 16) + w1 * __uint_as_float(v1.y << 16)
          + w2 * __uint_as_float(v2.y << 16) + w3 * __uint_as_float(v3.y << 16);
        b2 = fmaxf(b2, s);
        s = w0 * __uint_as_float(v0.y & 0xffff0000u) + w1 * __uint_as_float(v1.y & 0xffff0000u)
          + w2 * __uint_as_float(v2.y & 0xffff0000u) + w3 * __uint_as_float(v3.y & 0xffff0000u);
        b3 = fmaxf(b3, s);
        s = w0 * __uint_as_float(v0.z << 16) + w1 * __uint_as_float(v1.z << 16)
          + w2 * __uint_as_float(v2.z << 16) + w3 * __uint_as_float(v3.z << 16);
        b4 = fmaxf(b4, s);
        s = w0 * __uint_as_float(v0.z & 0xffff0000u) + w1 * __uint_as_float(v1.z & 0xffff0000u)
          + w2 * __uint_as_float(v2.z & 0xffff0000u) + w3 * __uint_as_float(v3.z & 0xffff0000u);
        b5 = fmaxf(b5, s);
        s = w0 * __uint_as_float(v0.w << 16) + w1 * __uint_as_float(v1.w << 16)
          + w2 * __uint_as_float(v2.w << 16) + w3 * __uint_as_float(v3.w << 16);
        b6 = fmaxf(b6, s);
        s = w0 * __uint_as_float(v0.w & 0xffff0000u) + w1 * __uint_as_float(v1.w & 0xffff0000u)
          + w2 * __uint_as_float(v2.w & 0xffff0000u) + w3 * __uint_as_float(v3.w & 0xffff0000u);
        b7 = fmaxf(b7, s);
    }
    union { __hip_bfloat16 hh[8]; uint4 u; } pk;
    pk.hh[0] = __float2bfloat16(b0);
    pk.hh[1] = __float2bfloat16(b1);
    pk.hh[2] = __float2bfloat16(b2);
    pk.hh[3] = __float2bfloat16(b3);
    pk.hh[4] = __float2bfloat16(b4);
    pk.hh[5] = __float2bfloat16(b5);
    pk.hh[6] = __float2bfloat16(b6);
    pk.hh[7] = __float2bfloat16(b7);
    featw[point * 16 + t16] = pk.u;   // elements point*128 + 8*t16 ..+7
}

// ---------------------------------------------------------------------------
// MFMA bf16 GEMM, BK=64, DOUBLE-BUFFERED prefetch (R12-exact: best known).
// 128x128 tile, 4 waves 2x2, each wave 4x4 of 16x16x32 MFMA.
// stage(kt+1) issued BEFORE compute(kt): the vmcnt(0) drain at the barrier
// arrives after a full 64-k compute block, covering the L2/HBM fill.
// Tested & rejected: BK=32 dbuf (R13, barrier-frequency), 32x32 engine (R9),
// chunk rotation (R7), XOR swizzle (R15, neutral — conflicts unchanged).
// XCD-aware swizzle: lid%8 = XCD, n fastest -> A-tile reused within one XCD.
// ---------------------------------------------------------------------------
__global__ __launch_bounds__(256) void mfma_gemm(
    const __hip_bfloat16* __restrict__ A,   // (M, K) row-major
    const __hip_bfloat16* __restrict__ B,   // (N, K) row-major (= B^T)
    const float* __restrict__ bias,         // (N)
    __hip_bfloat16* __restrict__ out,       // (M, N)
    int M, int N, int K, int n_tiles)
{
    __shared__ __hip_bfloat16 As[2][128 * 64];   // 32 KB
    __shared__ __hip_bfloat16 Bs[2][128 * 64];   // 32 KB
    const int tid  = threadIdx.x;
    const int lane = tid & 63;
    const int wave = tid >> 6;
    const int wr = wave >> 1, wc = wave & 1;    // 2x2 wave grid
    const int quad = lane >> 4;
    const int l16  = lane & 15;

    // XCD-aware relabel (grid must be divisible by 8)
    const int lid = blockIdx.x;
    const int per = gridDim.x >> 3;
    const int g   = (lid & 7) * per + (lid >> 3);
    const int n0 = (g % n_tiles) * 128;
    const int m0 = (g / n_tiles) * 128;

    f32x4 acc[4][4];
#pragma unroll
    for (int i = 0; i < 4; ++i)
#pragma unroll
        for (int j = 0; j < 4; ++j) { f32x4 z = {0.f, 0.f, 0.f, 0.f}; acc[i][j] = z; }

    // ---- stage helper (4 sites x 256 thr x 16 B per matrix) ----
    auto stage = [&](int k0, int buf) {
#pragma unroll
        for (int s = 0; s < 4; ++s) {
            int li   = s * 256 + tid;          // chunk 0..1023
            int row  = (li & 511) >> 2;        // 0..127
            int ke   = (li >> 9) * 32 + (li & 3) * 8;  // k element offset 0..63
            const __hip_bfloat16* ga = A + (size_t)(m0 + row) * K + k0 + ke;
            const __hip_bfloat16* gb = B + (size_t)(n0 + row) * K + k0 + ke;
            int chunk = s * 256 + (tid & ~63); // wave-uniform base chunk
            __builtin_amdgcn_global_load_lds(
                (const __attribute__((address_space(1))) unsigned int*)ga,
                (__attribute__((address_space(3))) unsigned int*)(As[buf] + chunk * 8),
                16, 0, 0);
            __builtin_amdgcn_global_load_lds(
                (const __attribute__((address_space(1))) unsigned int*)gb,
                (__attribute__((address_space(3))) unsigned int*)(Bs[buf] + chunk * 8),
                16, 0, 0);
        }
    };

    const int nk = K >> 6;
    stage(0, 0);
    __syncthreads();                 // buffer 0 ready

    for (int kt = 0; kt < nk; ++kt) {
        const int cur = kt & 1;
        if (kt + 1 < nk) stage((kt + 1) << 6, cur ^ 1);   // async prefetch

        // ---- compute from buffer cur: two 32-k halves ----
#pragma unroll
        for (int kh = 0; kh < 2; ++kh) {
            const short* ap = (const short*)As[cur] + kh * 4096;
            const short* bp = (const short*)Bs[cur] + kh * 4096;
            short8 af[4], bf[4];
#pragma unroll
            for (int mt = 0; mt < 4; ++mt) {
                int row = wr * 64 + mt * 16 + l16;
                af[mt] = *(const short8*)(ap + row * 32 + quad * 8);
            }
#pragma unroll
            for (int nt = 0; nt < 4; ++nt) {
                int row = wc * 64 + nt * 16 + l16;
                bf[nt] = *(const short8*)(bp + row * 32 + quad * 8);
            }
#pragma unroll
            for (int mt = 0; mt < 4; ++mt)
#pragma unroll
                for (int nt = 0; nt < 4; ++nt)
                    acc[mt][nt] = __builtin_amdgcn_mfma_f32_16x16x32_bf16(
                        af[mt], bf[nt], acc[mt][nt], 0, 0, 0);
        }
        __syncthreads();   // drains prefetch (overlapped) + releases cur buffer
    }

    // ---- epilogue: C row = quad*4 + r, col = l16 ----
#pragma unroll
    for (int nt = 0; nt < 4; ++nt) {
        int n = n0 + wc * 64 + nt * 16 + l16;
        float bv = bias[n];
#pragma unroll
        for (int mt = 0; mt < 4; ++mt) {
            int mbase = m0 + wr * 64 + mt * 16 + quad * 4;
#pragma unroll
            for (int r = 0; r < 4; ++r) {
                float v = acc[mt][nt][r] + bv;
                v = v > 0.0f ? v : 0.0f;
                out[(size_t)(mbase + r) * N + n] = (__hip_bfloat16)v;
            }
        }
    }
}

// ---------------------------------------------------------------------------
// Head: one wave per line, uint4 x-loads (16 B/lane, 2 iters):
// logits[l][n] = sum_k x2[l][k]*w3[n][k] + b3[n]
// ---------------------------------------------------------------------------
__global__ __launch_bounds__(256) void head_kernel(
    const __hip_bfloat16* __restrict__ x2,  // (N_LINES, 1024) bf16
    const float* __restrict__ w3,           // (3, 1024)
    const float* __restrict__ b3,           // (3)
    float* __restrict__ out)                // (N_LINES, 3)
{
    const int gtid = blockIdx.x * blockDim.x + threadIdx.x;
    const int l = gtid >> 6;
    const int lane = threadIdx.x & 63;
    if (l >= N_LINES) return;
    const __hip_bfloat16* xr = x2 + (size_t)l * DIM_FC;
    float s0 = 0.0f, s1 = 0.0f, s2 = 0.0f;
#pragma unroll
    for (int it = 0; it < 2; ++it) {
        int k = it * 512 + lane * 8;
        uint4 xv = *(const uint4*)(xr + k);
        float x[8];
        x[0] = __uint_as_float(xv.x << 16);
        x[1] = __uint_as_float(xv.x & 0xffff0000u);
        x[2] = __uint_as_float(xv.y << 16);
        x[3] = __uint_as_float(xv.y & 0xffff0000u);
        x[4] = __uint_as_float(xv.z << 16);
        x[5] = __uint_as_float(xv.z & 0xffff0000u);
        x[6] = __uint_as_float(xv.w << 16);
        x[7] = __uint_as_float(xv.w & 0xffff0000u);
#pragma unroll
        for (int h = 0; h < 2; ++h) {
            int kk = k + h * 4;
            float4 wa = *(const float4*)(w3 + 0 * DIM_FC + kk);
            float4 wb = *(const float4*)(w3 + 1 * DIM_FC + kk);
            float4 wc = *(const float4*)(w3 + 2 * DIM_FC + kk);
            s0 += x[h*4+0] * wa.x + x[h*4+1] * wa.y + x[h*4+2] * wa.z + x[h*4+3] * wa.w;
            s1 += x[h*4+0] * wb.x + x[h*4+1] * wb.y + x[h*4+2] * wb.z + x[h*4+3] * wb.w;
            s2 += x[h*4+0] * wc.x + x[h*4+1] * wc.y + x[h*4+2] * wc.z + x[h*4+3] * wc.w;
        }
    }
#pragma unroll
    for (int off = 32; off > 0; off >>= 1) {
        s0 += __shfl_xor(s0, off);
        s1 += __shfl_xor(s1, off);
        s2 += __shfl_xor(s2, off);
    }
    if (lane == 0) {
        out[(size_t)l * 3 + 0] = s0 + b3[0];
        out[(size_t)l * 3 + 1] = s1 + b3[1];
        out[(size_t)l * 3 + 2] = s2 + b3[2];
    }
}

// ---------------------------------------------------------------------------
extern "C" void kernel_launch(void* const* d_in, const int* in_sizes, int n_in,
                              void* d_out, int out_size, void* d_ws, size_t ws_size,
                              hipStream_t stream) {
    const float* features = (const float*)d_in[0];  // (1,256,128,128)
    const float* lines    = (const float*)d_in[1];  // (16000,4)
    const float* w_fc1    = (const float*)d_in[2];  // (128,256)
    const float* b_fc1    = (const float*)d_in[3];  // (128)
    const float* w1       = (const float*)d_in[4];  // (1024,1024)
    const float* b1       = (const float*)d_in[5];  // (1024)
    const float* w2       = (const float*)d_in[6];  // (1024,1024)
    const float* b2       = (const float*)d_in[7];  // (1024)
    const float* w3       = (const float*)d_in[8];  // (3,1024)
    const float* b3       = (const float*)d_in[9];  // (3)
    float* out = (float*)d_out;

    char* ws = (char*)d_ws;
    __hip_bfloat16* loi    = (__hip_bfloat16*)ws;
    __hip_bfloat16* featb  = (__hip_bfloat16*)(ws + (size_t)8 * 1024 * 1024);
    __hip_bfloat16* x1b    = (__hip_bfloat16*)(ws + (size_t)40 * 1024 * 1024);
    __hip_bfloat16* x2b    = featb;   // reuse (featb dead after GEMM1)
    __hip_bfloat16* w1b    = (__hip_bfloat16*)(ws + (size_t)72 * 1024 * 1024);
    __hip_bfloat16* w2b    = (__hip_bfloat16*)(ws + (size_t)74 * 1024 * 1024);
    __hip_bfloat16* featsT = (__hip_bfloat16*)(ws + (size_t)76 * 1024 * 1024);
    __hip_bfloat16* wfc1b  = (__hip_bfloat16*)(ws + (size_t)84 * 1024 * 1024);

    // 0) all prep in one dispatch
    prep_kernel<<<dim3(3104), 256, 0, stream>>>(
        features, featsT, w1, w1b, w2, w2b, w_fc1, wfc1b);

    // 1) conv1x1 as MFMA GEMM (grid 128, 1 n-tile, K=256 -> 4 iters)
    mfma_gemm<<<dim3(NPIX / 128), 256, 0, stream>>>(
        featsT, wfc1b, b_fc1, loi, NPIX, DIM_LOI, C_IN, 1);

    // 2) line pooling -> featb (16000,1024) bf16, k' = p*128+c  (2 lines/block)
    pool_kernel<<<dim3(N_LINES / 2), 256, 0, stream>>>(loi, lines, featb);

    // 3) x1 = relu(feat @ w1p^T + b1)   grid 1000 = 125 m x 8 n
    mfma_gemm<<<dim3((N_LINES / 128) * (DIM_FC / 128)), 256, 0, stream>>>(
        featb, w1b, b1, x1b, N_LINES, DIM_FC, DIM_FC, DIM_FC / 128);

    // 4) x2 = relu(x1 @ w2^T + b2)
    mfma_gemm<<<dim3((N_LINES / 128) * (DIM_FC / 128)), 256, 0, stream>>>(
        x1b, w2b, b2, x2b, N_LINES, DIM_FC, DIM_FC, DIM_FC / 128);

    // 5) logits = x2 @ w3^T + b3
    head_kernel<<<dim3((N_LINES * 64 + 255) / 256), 256, 0, stream>>>(x2b, w3, b3, out);
}